// Round 9
// baseline (1143.080 us; speedup 1.0000x reference)
//
#include <hip/hip_runtime.h>
#include <stdint.h>

// ---- dims ----
// B=8, L=27, T=256, D=1152, GS=3, G=9, DD=512, H=8, HD=64, NQ=1, OD=2048
// Output dtype: FLOAT32 (verified round 4).
//
// Round 9: ALGEBRAIC RESTRUCTURE — projections eliminated.
//   scores = K·Qk (+const that cancels in softmax), Qk = (Qp·0.125)·Wk
//   pooled = (attn·V)·Wv + bv   (since sum_t attn = 1)
// => K,V each read ONCE; total FLOPs ~2.5G; memory-bound (~510 MB => ~81 us floor).
// All f32 — no bf16 intermediates at all.

// ---------------------------------------------------------------------------
// K1: Qp[l,f] = (query[l,:] @ Wq[g] + bq[g]) * 0.125
// grid (27,8), block 256: 64 f's per block, 4-way k-split, LDS reduce.
// ---------------------------------------------------------------------------
__global__ __launch_bounds__(256) void qproj(
    const float* __restrict__ query, const float* __restrict__ Wq,
    const float* __restrict__ bq, float* __restrict__ Qp)
{
  const int l = blockIdx.x, g = l / 3;
  const int fb = blockIdx.y * 64;
  __shared__ float q[1152];
  __shared__ float part[4][64];
  for (int i = threadIdx.x; i < 1152; i += 256) q[i] = query[(size_t)l * 1152 + i];
  __syncthreads();
  const int fi = threadIdx.x & 63;
  const int kq = threadIdx.x >> 6;            // 0..3, 288 d's each
  const float* W = Wq + (size_t)g * 1152 * 512 + fb + fi;
  float a0 = 0.f, a1 = 0.f;
  const int d0 = kq * 288;
#pragma unroll 4
  for (int d = d0; d < d0 + 288; d += 2) {
    a0 += q[d]     * W[(size_t)d * 512];
    a1 += q[d + 1] * W[(size_t)(d + 1) * 512];
  }
  part[kq][fi] = a0 + a1;
  __syncthreads();
  if (threadIdx.x < 64) {
    const int f = fb + threadIdx.x;
    float r = part[0][threadIdx.x] + part[1][threadIdx.x]
            + part[2][threadIdx.x] + part[3][threadIdx.x];
    Qp[l * 512 + f] = (r + bq[g * 512 + f]) * 0.125f;
  }
}

// ---------------------------------------------------------------------------
// K2: Qk[l,h,d] = sum_e Qp[l,h*64+e] * Wk[g,d,h*64+e]
// grid 27, block 512 (8 waves; wave = h, lane = e). Coalesced Wk rows,
// 64-lane butterfly reduce per d.
// ---------------------------------------------------------------------------
__global__ __launch_bounds__(512) void qk_mat(
    const float* __restrict__ Qp, const float* __restrict__ Wk,
    float* __restrict__ Qk)
{
  const int l = blockIdx.x, g = l / 3;
  const int f = threadIdx.x;          // 0..511
  const int h = f >> 6;               // wave index = head
  const int lane = f & 63;            // e
  const float qv = Qp[l * 512 + f];
  const float* W = Wk + (size_t)g * 1152 * 512 + f;
  float* dst = Qk + ((size_t)l * 8 + h) * 1152;
#pragma unroll 4
  for (int d = 0; d < 1152; d++) {
    float p = qv * W[(size_t)d * 512];
#pragma unroll
    for (int o = 32; o >= 1; o >>= 1) p += __shfl_xor(p, o, 64);
    if (lane == 0) dst[d] = p;
  }
}

// ---------------------------------------------------------------------------
// K3: fused scores -> softmax -> VA = attn @ V, per (b,l). grid 216, block 256.
//   scores: thread = token t, 8 dots of 1152 (Qk via uniform/scalar loads)
//   softmax: 64-lane butterfly + cross-wave LDS reduce (8 heads)
//   VA: wave = head-pair, lane strides d in float4 (coalesced V reads)
// ---------------------------------------------------------------------------
__global__ __launch_bounds__(256) void attn_va(
    const float* __restrict__ K, const float* __restrict__ V,
    const float* __restrict__ Qk, float* __restrict__ VA)
{
  const int bl = blockIdx.x;          // 0..215 (= b*27 + l)
  const int l = bl % 27;
  const int tid = threadIdx.x;
  const int wid = tid >> 6, lane = tid & 63;

  __shared__ float attn_s[8][256];
  __shared__ float red[4][8];
  __shared__ float red2[4][8];

  // ---- scores: thread = token ----
  const float4* Kr = (const float4*)(K + ((size_t)bl * 256 + tid) * 1152);
  const float* Qkl = Qk + (size_t)l * 8 * 1152;
  float sc[8] = {0.f, 0.f, 0.f, 0.f, 0.f, 0.f, 0.f, 0.f};
  for (int i = 0; i < 288; i++) {
    const float4 kv = Kr[i];
    const int d = i * 4;
#pragma unroll
    for (int h = 0; h < 8; h++) {
      const float* q = Qkl + h * 1152 + d;   // uniform across lanes -> s_load
      sc[h] = fmaf(kv.x, q[0], sc[h]);
      sc[h] = fmaf(kv.y, q[1], sc[h]);
      sc[h] = fmaf(kv.z, q[2], sc[h]);
      sc[h] = fmaf(kv.w, q[3], sc[h]);
    }
  }

  // ---- softmax over 256 tokens, per head ----
#pragma unroll
  for (int h = 0; h < 8; h++) {
    float m = sc[h];
#pragma unroll
    for (int o = 1; o < 64; o <<= 1) m = fmaxf(m, __shfl_xor(m, o, 64));
    if (lane == 0) red[wid][h] = m;
  }
  __syncthreads();
  float p[8];
#pragma unroll
  for (int h = 0; h < 8; h++) {
    const float M = fmaxf(fmaxf(red[0][h], red[1][h]), fmaxf(red[2][h], red[3][h]));
    p[h] = __expf(sc[h] - M);
    float s = p[h];
#pragma unroll
    for (int o = 1; o < 64; o <<= 1) s += __shfl_xor(s, o, 64);
    if (lane == 0) red2[wid][h] = s;
  }
  __syncthreads();
#pragma unroll
  for (int h = 0; h < 8; h++) {
    const float S = red2[0][h] + red2[1][h] + red2[2][h] + red2[3][h];
    attn_s[h][tid] = p[h] * (1.0f / S);
  }
  __syncthreads();

  // ---- VA[h,d] = sum_t attn[h,t] * V[t,d]; wave = head pair ----
  const int h0 = wid * 2, h1 = h0 + 1;
  const float* Vbl = V + (size_t)bl * 256 * 1152;
  float4 va0[5], va1[5];
#pragma unroll
  for (int k = 0; k < 5; k++) {
    va0[k] = make_float4(0.f, 0.f, 0.f, 0.f);
    va1[k] = make_float4(0.f, 0.f, 0.f, 0.f);
  }
  for (int t = 0; t < 256; t++) {
    const float a0 = attn_s[h0][t];   // broadcast LDS read
    const float a1 = attn_s[h1][t];
    const float4* Vr = (const float4*)(Vbl + (size_t)t * 1152) + lane;
#pragma unroll
    for (int k = 0; k < 4; k++) {
      const float4 vv = Vr[k * 64];   // d = k*256 + lane*4 (coalesced)
      va0[k].x = fmaf(a0, vv.x, va0[k].x); va0[k].y = fmaf(a0, vv.y, va0[k].y);
      va0[k].z = fmaf(a0, vv.z, va0[k].z); va0[k].w = fmaf(a0, vv.w, va0[k].w);
      va1[k].x = fmaf(a1, vv.x, va1[k].x); va1[k].y = fmaf(a1, vv.y, va1[k].y);
      va1[k].z = fmaf(a1, vv.z, va1[k].z); va1[k].w = fmaf(a1, vv.w, va1[k].w);
    }
    if (lane < 32) {
      const float4 vv = Vr[256];      // d = 1024 + lane*4
      va0[4].x = fmaf(a0, vv.x, va0[4].x); va0[4].y = fmaf(a0, vv.y, va0[4].y);
      va0[4].z = fmaf(a0, vv.z, va0[4].z); va0[4].w = fmaf(a0, vv.w, va0[4].w);
      va1[4].x = fmaf(a1, vv.x, va1[4].x); va1[4].y = fmaf(a1, vv.y, va1[4].y);
      va1[4].z = fmaf(a1, vv.z, va1[4].z); va1[4].w = fmaf(a1, vv.w, va1[4].w);
    }
  }
  float4* dst0 = (float4*)(VA + ((size_t)bl * 8 + h0) * 1152);
  float4* dst1 = (float4*)(VA + ((size_t)bl * 8 + h1) * 1152);
#pragma unroll
  for (int k = 0; k < 4; k++) {
    dst0[k * 64 + lane] = va0[k];
    dst1[k * 64 + lane] = va1[k];
  }
  if (lane < 32) {
    dst0[256 + lane] = va0[4];
    dst1[256 + lane] = va1[4];
  }
}

// ---------------------------------------------------------------------------
// K4: pooled[b,l, e*8+h] = sum_d VA[b,l,h,d] * Wv[g,d,h*64+e] + bv[g,h*64+e]
// grid (27,8) = (l,h); block 512 = 8 waves (wave = b), lane = e.
// ---------------------------------------------------------------------------
__global__ __launch_bounds__(512) void pv_mat(
    const float* __restrict__ VA, const float* __restrict__ Wv,
    const float* __restrict__ bv, float* __restrict__ pooled)
{
  const int l = blockIdx.x, g = l / 3, h = blockIdx.y;
  const int b = threadIdx.x >> 6, lane = threadIdx.x & 63;
  const float* W = Wv + (size_t)g * 1152 * 512 + h * 64 + lane;
  const float* va = VA + (((size_t)(b * 27 + l)) * 8 + h) * 1152;  // wave-uniform
  float acc = 0.f;
#pragma unroll 4
  for (int d = 0; d < 1152; d++)
    acc = fmaf(va[d], W[(size_t)d * 512], acc);
  pooled[(size_t)(b * 27 + l) * 512 + lane * 8 + h] = acc + bv[g * 512 + h * 64 + lane];
}

// ---------------------------------------------------------------------------
// K5: out[b,l,n] = pooled[b,l,:] @ Wo[g] + bo[g]   (f32)
// grid (27,8), block 256, one n per thread, 8 b's per thread.
// ---------------------------------------------------------------------------
__global__ __launch_bounds__(256) void out_gemm(
    const float* __restrict__ pooled, const float* __restrict__ Wo,
    const float* __restrict__ bo, float* __restrict__ out)
{
  const int l = blockIdx.x, g = l / 3;
  const int n = blockIdx.y * 256 + threadIdx.x;
  __shared__ float pl[8][512];
  for (int i = threadIdx.x; i < 4096; i += 256) {
    const int b = i >> 9, f = i & 511;
    pl[b][f] = pooled[(size_t)(b * 27 + l) * 512 + f];
  }
  __syncthreads();
  const float* W = Wo + (size_t)g * 512 * 2048 + n;
  float acc[8] = {0.f, 0.f, 0.f, 0.f, 0.f, 0.f, 0.f, 0.f};
#pragma unroll 4
  for (int f = 0; f < 512; f++) {
    const float w = W[(size_t)f * 2048];
#pragma unroll
    for (int b = 0; b < 8; b++) acc[b] += pl[b][f] * w;
  }
  const float bb = bo[g * 2048 + n];
#pragma unroll
  for (int b = 0; b < 8; b++)
    out[(size_t)(b * 27 + l) * 2048 + n] = acc[b] + bb;
}

// ---------------------------------------------------------------------------
// sentinel: zero-fill f32 output (absmax would read ~1.06e-1 = max|ref|)
// ---------------------------------------------------------------------------
__global__ __launch_bounds__(256) void zfill(float* __restrict__ out, int n) {
  const int i = blockIdx.x * 256 + threadIdx.x;
  if (i < n) out[i] = 0.f;
}

// ---------------------------------------------------------------------------
extern "C" void kernel_launch(void* const* d_in, const int* in_sizes, int n_in,
                              void* d_out, int out_size, void* d_ws, size_t ws_size,
                              hipStream_t stream)
{
  float* out = (float*)d_out;   // f32 output (verified round 4)

  // ---- config guards ----
  bool ok = (n_in == 11) && (out_size == 8 * 27 * 2048);
  if (ok) {
    const int expect[11] = {
      8 * 27 * 256 * 1152,  // K
      8 * 27 * 256 * 1152,  // V
      27 * 1 * 1152,        // query
      9 * 1152 * 512,       // Wq
      9 * 512,              // bq
      9 * 1152 * 512,       // Wk
      9 * 512,              // bk
      9 * 1152 * 512,       // Wv
      9 * 512,              // bv
      9 * 512 * 2048,       // Wo
      9 * 2048              // bo
    };
    for (int i = 0; i < 11; i++) ok = ok && (in_sizes[i] == expect[i]);
  }
  // ws layout (bytes):
  //   Qp     @ 0         :    55,296
  //   Qk     @ 55,296    :   995,328
  //   VA     @ 1,050,624 : 7,962,624
  //   pooled @ 9,013,248 :   442,368   -> NEED 9,455,616
  const size_t NEED = 9455616;
  ok = ok && (ws_size >= NEED);

  if (!ok) {
    zfill<<<dim3((out_size + 255) / 256), dim3(256), 0, stream>>>(out, out_size);
    return;
  }

  const float* Kin   = (const float*)d_in[0];
  const float* Vin   = (const float*)d_in[1];
  const float* query = (const float*)d_in[2];
  const float* Wq    = (const float*)d_in[3];
  const float* bq    = (const float*)d_in[4];
  const float* Wk    = (const float*)d_in[5];
  const float* Wv    = (const float*)d_in[7];
  const float* bvp   = (const float*)d_in[8];
  const float* Wo    = (const float*)d_in[9];
  const float* bo    = (const float*)d_in[10];
  // bk (d_in[6]) is unused: its score contribution is constant over t and
  // cancels in softmax exactly.

  char* ws = (char*)d_ws;
  float* Qpw     = (float*)(ws);
  float* Qkw     = (float*)(ws + 55296);
  float* VAw     = (float*)(ws + 1050624);
  float* pooledw = (float*)(ws + 9013248);

  qproj  <<<dim3(27, 8), dim3(256), 0, stream>>>(query, Wq, bq, Qpw);
  qk_mat <<<dim3(27),    dim3(512), 0, stream>>>(Qpw, Wk, Qkw);
  attn_va<<<dim3(216),   dim3(256), 0, stream>>>(Kin, Vin, Qkw, VAw);
  pv_mat <<<dim3(27, 8), dim3(512), 0, stream>>>(VAw, Wv, bvp, pooledw);
  out_gemm<<<dim3(27, 8), dim3(256), 0, stream>>>(pooledw, Wo, bo, out);
}

// Round 10
// 478.401 us; speedup vs baseline: 2.3894x; 2.3894x over previous
//
#include <hip/hip_runtime.h>
#include <stdint.h>

// ---- dims ----
// B=8, L=27, T=256, D=1152, GS=3, G=9, DD=512, H=8, HD=64, NQ=1, OD=2048
// Output dtype: FLOAT32 (verified round 4).
//
// Round 10: fix the two parallelism disasters found in round-9 profile.
//   qk_mat : 27 blocks/butterfly-serial -> 972 blocks, thread-per-(l,h,d)
//   attn_va: 256-thread blocks (<1 wave/SIMD) -> 1024-thread blocks,
//            4-way d-split scores + 16-wave (head x token-half) VA.
// Algebra (round 9, verified): scores = K·Qk (bk cancels in softmax);
// pooled = (attn·V)·Wv + bv. All f32.

// ---------------------------------------------------------------------------
// K1: Qp[l,f] = (query[l,:] @ Wq[g] + bq[g]) * 0.125
// grid (27,8), block 256: 64 f's per block, 4-way k-split, LDS reduce.
// ---------------------------------------------------------------------------
__global__ __launch_bounds__(256) void qproj(
    const float* __restrict__ query, const float* __restrict__ Wq,
    const float* __restrict__ bq, float* __restrict__ Qp)
{
  const int l = blockIdx.x, g = l / 3;
  const int fb = blockIdx.y * 64;
  __shared__ float q[1152];
  __shared__ float part[4][64];
  for (int i = threadIdx.x; i < 1152; i += 256) q[i] = query[(size_t)l * 1152 + i];
  __syncthreads();
  const int fi = threadIdx.x & 63;
  const int kq = threadIdx.x >> 6;            // 0..3, 288 d's each
  const float* W = Wq + (size_t)g * 1152 * 512 + fb + fi;
  float a0 = 0.f, a1 = 0.f;
  const int d0 = kq * 288;
#pragma unroll 4
  for (int d = d0; d < d0 + 288; d += 2) {
    a0 += q[d]     * W[(size_t)d * 512];
    a1 += q[d + 1] * W[(size_t)(d + 1) * 512];
  }
  part[kq][fi] = a0 + a1;
  __syncthreads();
  if (threadIdx.x < 64) {
    const int f = fb + threadIdx.x;
    float r = part[0][threadIdx.x] + part[1][threadIdx.x]
            + part[2][threadIdx.x] + part[3][threadIdx.x];
    Qp[l * 512 + f] = (r + bq[g * 512 + f]) * 0.125f;
  }
}

// ---------------------------------------------------------------------------
// K2: Qk[l,h,d] = sum_e Qp[l,h*64+e] * Wk[g,d,h*64+e]
// grid 972, block 256: one thread per (l,h,d). float4 serial dot of 64.
// Wave working set = 64 lanes x 256B = 16KB (L1-resident).
// ---------------------------------------------------------------------------
__global__ __launch_bounds__(256) void qk_mat(
    const float* __restrict__ Qp, const float* __restrict__ Wk,
    float* __restrict__ Qk)
{
  const int idx = blockIdx.x * 256 + threadIdx.x;  // 0..248831
  const int l   = idx / 9216;
  const int rem = idx % 9216;
  const int h   = rem / 1152;
  const int d   = rem % 1152;
  const int g   = l / 3;
  const float4* q4 = (const float4*)(Qp + l * 512 + h * 64);
  const float4* w4 = (const float4*)(Wk + (size_t)g * 1152 * 512 + (size_t)d * 512 + h * 64);
  float acc = 0.f;
#pragma unroll
  for (int e = 0; e < 16; e++) {
    const float4 a = q4[e], b = w4[e];
    acc += a.x * b.x + a.y * b.y + a.z * b.z + a.w * b.w;
  }
  Qk[((size_t)l * 8 + h) * 1152 + d] = acc;
}

// ---------------------------------------------------------------------------
// K3: fused scores -> softmax -> VA = attn @ V, per (b,l).
// grid 216, block 1024 (16 waves).
//   phase 1: thread (t, dq) partial-scores over d-quarter -> psc[4][8][256]
//   softmax: threads t<256 reduce quarters, butterfly + cross-wave LDS
//   phase 2: wave = (head, token-half); halves combined via LDS vasm
// LDS: attn 8KB + red 256B + union(psc 32KB, vasm 36.9KB) = ~45.3KB
// ---------------------------------------------------------------------------
__global__ __launch_bounds__(1024) void attn_va(
    const float* __restrict__ K, const float* __restrict__ V,
    const float* __restrict__ Qk, float* __restrict__ VA)
{
  const int bl = blockIdx.x;          // 0..215 (= b*27 + l)
  const int l = bl % 27;
  const int tid = threadIdx.x;
  const int wid = tid >> 6, lane = tid & 63;

  __shared__ float attn_s[8][256];
  __shared__ float red[4][8];
  __shared__ float red2[4][8];
  __shared__ __align__(16) char ubuf[36864];   // psc[4][8][256] / vasm[8][1152]
  float (*psc)[8][256] = (float (*)[8][256])ubuf;
  float* vasm = (float*)ubuf;

  // ---- phase 1: partial scores; thread = (token t, d-quarter dq) ----
  {
    const int t  = tid & 255;
    const int dq = tid >> 8;          // 0..3
    const float4* Kr = (const float4*)(K + ((size_t)bl * 256 + t) * 1152) + dq * 72;
    const float* Qkl = Qk + (size_t)l * 8 * 1152 + dq * 288;
    float sc[8] = {0.f, 0.f, 0.f, 0.f, 0.f, 0.f, 0.f, 0.f};
    for (int i = 0; i < 72; i++) {
      const float4 kv = Kr[i];
      const int d = i * 4;
#pragma unroll
      for (int h = 0; h < 8; h++) {
        const float* q = Qkl + h * 1152 + d;   // wave-uniform -> s_load
        sc[h] = fmaf(kv.x, q[0], sc[h]);
        sc[h] = fmaf(kv.y, q[1], sc[h]);
        sc[h] = fmaf(kv.z, q[2], sc[h]);
        sc[h] = fmaf(kv.w, q[3], sc[h]);
      }
    }
#pragma unroll
    for (int h = 0; h < 8; h++) psc[dq][h][t] = sc[h];
  }
  __syncthreads();

  // ---- softmax over 256 tokens, per head (threads t<256 active) ----
  const bool act = (tid < 256);
  float p[8], scl[8];
  if (act) {
#pragma unroll
    for (int h = 0; h < 8; h++) {
      scl[h] = psc[0][h][tid] + psc[1][h][tid] + psc[2][h][tid] + psc[3][h][tid];
      float m = scl[h];
#pragma unroll
      for (int o = 1; o < 64; o <<= 1) m = fmaxf(m, __shfl_xor(m, o, 64));
      if (lane == 0) red[wid][h] = m;
    }
  }
  __syncthreads();
  if (act) {
#pragma unroll
    for (int h = 0; h < 8; h++) {
      const float M = fmaxf(fmaxf(red[0][h], red[1][h]), fmaxf(red[2][h], red[3][h]));
      p[h] = __expf(scl[h] - M);
      float s = p[h];
#pragma unroll
      for (int o = 1; o < 64; o <<= 1) s += __shfl_xor(s, o, 64);
      if (lane == 0) red2[wid][h] = s;
    }
  }
  __syncthreads();
  if (act) {
#pragma unroll
    for (int h = 0; h < 8; h++) {
      const float S = red2[0][h] + red2[1][h] + red2[2][h] + red2[3][h];
      attn_s[h][tid] = p[h] * (1.0f / S);
    }
  }
  __syncthreads();   // also separates psc reads from vasm writes

  // ---- phase 2: VA[h,d] = sum_t attn[h,t] * V[t,d] ----
  // wave = (head h, token-half); halves combined via LDS.
  const int h = wid >> 1, half = wid & 1;
  const float* Vbl = V + (size_t)bl * 256 * 1152;
  float4 va[5];
#pragma unroll
  for (int k = 0; k < 5; k++) va[k] = make_float4(0.f, 0.f, 0.f, 0.f);
  const int tbeg = half * 128;
  for (int t = tbeg; t < tbeg + 128; t++) {
    const float a = attn_s[h][t];     // LDS broadcast
    const float4* Vr = (const float4*)(Vbl + (size_t)t * 1152) + lane;
#pragma unroll
    for (int k = 0; k < 4; k++) {
      const float4 vv = Vr[k * 64];   // d = k*256 + lane*4 (coalesced)
      va[k].x = fmaf(a, vv.x, va[k].x); va[k].y = fmaf(a, vv.y, va[k].y);
      va[k].z = fmaf(a, vv.z, va[k].z); va[k].w = fmaf(a, vv.w, va[k].w);
    }
    if (lane < 32) {
      const float4 vv = Vr[256];      // d = 1024 + lane*4
      va[4].x = fmaf(a, vv.x, va[4].x); va[4].y = fmaf(a, vv.y, va[4].y);
      va[4].z = fmaf(a, vv.z, va[4].z); va[4].w = fmaf(a, vv.w, va[4].w);
    }
  }
  if (half == 0) {
#pragma unroll
    for (int k = 0; k < 4; k++)
      *(float4*)&vasm[h * 1152 + k * 256 + lane * 4] = va[k];
    if (lane < 32)
      *(float4*)&vasm[h * 1152 + 1024 + lane * 4] = va[4];
  }
  __syncthreads();
  if (half == 1) {
    float4* dst = (float4*)(VA + ((size_t)bl * 8 + h) * 1152);
#pragma unroll
    for (int k = 0; k < 4; k++) {
      float4 o = *(const float4*)&vasm[h * 1152 + k * 256 + lane * 4];
      o.x += va[k].x; o.y += va[k].y; o.z += va[k].z; o.w += va[k].w;
      dst[k * 64 + lane] = o;
    }
    if (lane < 32) {
      float4 o = *(const float4*)&vasm[h * 1152 + 1024 + lane * 4];
      o.x += va[4].x; o.y += va[4].y; o.z += va[4].z; o.w += va[4].w;
      dst[256 + lane] = o;
    }
  }
}

// ---------------------------------------------------------------------------
// K4: pooled[b,l, e*8+h] = sum_d VA[b,l,h,d] * Wv[g,d,h*64+e] + bv[g,h*64+e]
// grid (27,8) = (l,h); block 512 = 8 waves (wave = b), lane = e.
// ---------------------------------------------------------------------------
__global__ __launch_bounds__(512) void pv_mat(
    const float* __restrict__ VA, const float* __restrict__ Wv,
    const float* __restrict__ bv, float* __restrict__ pooled)
{
  const int l = blockIdx.x, g = l / 3, h = blockIdx.y;
  const int b = threadIdx.x >> 6, lane = threadIdx.x & 63;
  const float* W = Wv + (size_t)g * 1152 * 512 + h * 64 + lane;
  const float* va = VA + (((size_t)(b * 27 + l)) * 8 + h) * 1152;  // wave-uniform
  float acc = 0.f;
#pragma unroll 4
  for (int d = 0; d < 1152; d++)
    acc = fmaf(va[d], W[(size_t)d * 512], acc);
  pooled[(size_t)(b * 27 + l) * 512 + lane * 8 + h] = acc + bv[g * 512 + h * 64 + lane];
}

// ---------------------------------------------------------------------------
// K5: out[b,l,n] = pooled[b,l,:] @ Wo[g] + bo[g]   (f32)
// grid (27,8), block 256, one n per thread, 8 b's per thread.
// ---------------------------------------------------------------------------
__global__ __launch_bounds__(256) void out_gemm(
    const float* __restrict__ pooled, const float* __restrict__ Wo,
    const float* __restrict__ bo, float* __restrict__ out)
{
  const int l = blockIdx.x, g = l / 3;
  const int n = blockIdx.y * 256 + threadIdx.x;
  __shared__ float pl[8][512];
  for (int i = threadIdx.x; i < 4096; i += 256) {
    const int b = i >> 9, f = i & 511;
    pl[b][f] = pooled[(size_t)(b * 27 + l) * 512 + f];
  }
  __syncthreads();
  const float* W = Wo + (size_t)g * 512 * 2048 + n;
  float acc[8] = {0.f, 0.f, 0.f, 0.f, 0.f, 0.f, 0.f, 0.f};
#pragma unroll 4
  for (int f = 0; f < 512; f++) {
    const float w = W[(size_t)f * 2048];
#pragma unroll
    for (int b = 0; b < 8; b++) acc[b] += pl[b][f] * w;
  }
  const float bb = bo[g * 2048 + n];
#pragma unroll
  for (int b = 0; b < 8; b++)
    out[(size_t)(b * 27 + l) * 2048 + n] = acc[b] + bb;
}

// ---------------------------------------------------------------------------
// sentinel: zero-fill f32 output (absmax would read ~1.06e-1 = max|ref|)
// ---------------------------------------------------------------------------
__global__ __launch_bounds__(256) void zfill(float* __restrict__ out, int n) {
  const int i = blockIdx.x * 256 + threadIdx.x;
  if (i < n) out[i] = 0.f;
}

// ---------------------------------------------------------------------------
extern "C" void kernel_launch(void* const* d_in, const int* in_sizes, int n_in,
                              void* d_out, int out_size, void* d_ws, size_t ws_size,
                              hipStream_t stream)
{
  float* out = (float*)d_out;   // f32 output (verified round 4)

  // ---- config guards ----
  bool ok = (n_in == 11) && (out_size == 8 * 27 * 2048);
  if (ok) {
    const int expect[11] = {
      8 * 27 * 256 * 1152,  // K
      8 * 27 * 256 * 1152,  // V
      27 * 1 * 1152,        // query
      9 * 1152 * 512,       // Wq
      9 * 512,              // bq
      9 * 1152 * 512,       // Wk
      9 * 512,              // bk
      9 * 1152 * 512,       // Wv
      9 * 512,              // bv
      9 * 512 * 2048,       // Wo
      9 * 2048              // bo
    };
    for (int i = 0; i < 11; i++) ok = ok && (in_sizes[i] == expect[i]);
  }
  // ws layout (bytes):
  //   Qp     @ 0         :    55,296
  //   Qk     @ 55,296    :   995,328
  //   VA     @ 1,050,624 : 7,962,624
  //   pooled @ 9,013,248 :   442,368   -> NEED 9,455,616
  const size_t NEED = 9455616;
  ok = ok && (ws_size >= NEED);

  if (!ok) {
    zfill<<<dim3((out_size + 255) / 256), dim3(256), 0, stream>>>(out, out_size);
    return;
  }

  const float* Kin   = (const float*)d_in[0];
  const float* Vin   = (const float*)d_in[1];
  const float* query = (const float*)d_in[2];
  const float* Wq    = (const float*)d_in[3];
  const float* bq    = (const float*)d_in[4];
  const float* Wk    = (const float*)d_in[5];
  const float* Wv    = (const float*)d_in[7];
  const float* bvp   = (const float*)d_in[8];
  const float* Wo    = (const float*)d_in[9];
  const float* bo    = (const float*)d_in[10];
  // bk (d_in[6]) unused: constant over t, cancels in softmax exactly.

  char* ws = (char*)d_ws;
  float* Qpw     = (float*)(ws);
  float* Qkw     = (float*)(ws + 55296);
  float* VAw     = (float*)(ws + 1050624);
  float* pooledw = (float*)(ws + 9013248);

  qproj  <<<dim3(27, 8), dim3(256),  0, stream>>>(query, Wq, bq, Qpw);
  qk_mat <<<dim3(972),   dim3(256),  0, stream>>>(Qpw, Wk, Qkw);
  attn_va<<<dim3(216),   dim3(1024), 0, stream>>>(Kin, Vin, Qkw, VAw);
  pv_mat <<<dim3(27, 8), dim3(512),  0, stream>>>(VAw, Wv, bvp, pooledw);
  out_gemm<<<dim3(27, 8), dim3(256), 0, stream>>>(pooledw, Wo, bo, out);
}

// Round 11
// 443.411 us; speedup vs baseline: 2.5779x; 1.0789x over previous
//
#include <hip/hip_runtime.h>
#include <stdint.h>

// ---- dims ----
// B=8, L=27, T=256, D=1152, GS=3, G=9, DD=512, H=8, HD=64, NQ=1, OD=2048
// Output dtype: FLOAT32 (verified round 4).
//
// Round 11: coalescing fixes from round-10 profile (attn_va latency-bound,
// hbm 13.5%, VALU 12.5%):
//   attn_va: wave = (token-group 32, head-half 4); lanes split d ->
//            coalesced K/V wave-loads; hoisted Qk frags (72 VGPR);
//            butterfly score reduce; LDS-atomic (rotated-component) combine.
//   qk_mat : 4 lanes per (l,h,d), e-split 16 -> coalesced 256B quads.
// Algebra (verified r9/r10): scores = K·Qk (bk cancels in softmax);
// pooled = (attn·V)·Wv + bv. All f32.

// ---------------------------------------------------------------------------
// K1: Qp[l,f] = (query[l,:] @ Wq[g] + bq[g]) * 0.125
// grid (27,8), block 256.
// ---------------------------------------------------------------------------
__global__ __launch_bounds__(256) void qproj(
    const float* __restrict__ query, const float* __restrict__ Wq,
    const float* __restrict__ bq, float* __restrict__ Qp)
{
  const int l = blockIdx.x, g = l / 3;
  const int fb = blockIdx.y * 64;
  __shared__ float q[1152];
  __shared__ float part[4][64];
  for (int i = threadIdx.x; i < 1152; i += 256) q[i] = query[(size_t)l * 1152 + i];
  __syncthreads();
  const int fi = threadIdx.x & 63;
  const int kq = threadIdx.x >> 6;            // 0..3, 288 d's each
  const float* W = Wq + (size_t)g * 1152 * 512 + fb + fi;
  float a0 = 0.f, a1 = 0.f;
  const int d0 = kq * 288;
#pragma unroll 4
  for (int d = d0; d < d0 + 288; d += 2) {
    a0 += q[d]     * W[(size_t)d * 512];
    a1 += q[d + 1] * W[(size_t)(d + 1) * 512];
  }
  part[kq][fi] = a0 + a1;
  __syncthreads();
  if (threadIdx.x < 64) {
    const int f = fb + threadIdx.x;
    float r = part[0][threadIdx.x] + part[1][threadIdx.x]
            + part[2][threadIdx.x] + part[3][threadIdx.x];
    Qp[l * 512 + f] = (r + bq[g * 512 + f]) * 0.125f;
  }
}

// ---------------------------------------------------------------------------
// K2: Qk[l,h,d] = sum_e Qp[l,h*64+e] * Wk[g,d,h*64+e]
// grid 3888, block 256: 4 threads per (l,h,d), each 16 e's (coalesced 256B
// per quad), 2-level shuffle reduce.
// ---------------------------------------------------------------------------
__global__ __launch_bounds__(256) void qk_mat(
    const float* __restrict__ Qp, const float* __restrict__ Wk,
    float* __restrict__ Qk)
{
  const int gidx = blockIdx.x * 256 + threadIdx.x;  // 0..995327
  const int eg   = gidx & 3;
  const int item = gidx >> 2;         // 0..248831 = (l,h,d)
  const int l    = item / 9216;
  const int rem  = item % 9216;
  const int h    = rem / 1152;
  const int d    = rem % 1152;
  const int g    = l / 3;
  const float4* q4 = (const float4*)(Qp + l * 512 + h * 64 + eg * 16);
  const float4* w4 = (const float4*)(Wk + (size_t)g * 1152 * 512 + (size_t)d * 512 + h * 64 + eg * 16);
  float acc = 0.f;
#pragma unroll
  for (int e = 0; e < 4; e++) {
    const float4 a = q4[e], b = w4[e];
    acc += a.x * b.x + a.y * b.y + a.z * b.z + a.w * b.w;
  }
  acc += __shfl_xor(acc, 1, 64);
  acc += __shfl_xor(acc, 2, 64);
  if (eg == 0) Qk[((size_t)l * 8 + h) * 1152 + d] = acc;
}

// ---------------------------------------------------------------------------
// K3: fused scores -> softmax -> VA = attn @ V, per (b,l).
// grid 216, block 1024 (16 waves). wave = (tg = token-group of 32, hp = head
// half of 4). Lanes split d: d = j*256 + lane*4 (j<4) and 1024 + lane*2.
// ---------------------------------------------------------------------------
__global__ __launch_bounds__(1024) void attn_va(
    const float* __restrict__ K, const float* __restrict__ V,
    const float* __restrict__ Qk, float* __restrict__ VA)
{
  const int bl = blockIdx.x;          // 0..215 (= b*27 + l)
  const int l = bl % 27;
  const int tid = threadIdx.x;
  const int wid = tid >> 6, lane = tid & 63;
  const int tg = wid >> 1;            // 0..7  (tokens tg*32..+32)
  const int hp = wid & 1;             // 0..1  (heads hp*4..+4)

  __shared__ float sc_s[8][256];      // scores, then attn in-place (8 KB)
  __shared__ float red[4][8], red2[4][8];
  __shared__ float vasm[8][1152];     // 36 KB combine buffer

  // ---- hoist Qk fragments: 4 heads x (4 float4 + float2) = 72 VGPR ----
  const float* Qkl = Qk + (size_t)l * 8 * 1152;
  float4 qf[4][4]; float2 q2[4];
#pragma unroll
  for (int hh = 0; hh < 4; hh++) {
    const float* qh = Qkl + (hp * 4 + hh) * 1152;
#pragma unroll
    for (int j = 0; j < 4; j++)
      qf[hh][j] = *(const float4*)(qh + j * 256 + lane * 4);
    q2[hh] = *(const float2*)(qh + 1024 + lane * 2);
  }

  // ---- phase 1: scores (coalesced K wave-loads, butterfly reduce) ----
  const int t0 = tg * 32;
  for (int tt = 0; tt < 32; tt++) {
    const int t = t0 + tt;
    const float* Krow = K + ((size_t)bl * 256 + t) * 1152;
    float4 kf[4];
#pragma unroll
    for (int j = 0; j < 4; j++) kf[j] = *(const float4*)(Krow + j * 256 + lane * 4);
    const float2 k2 = *(const float2*)(Krow + 1024 + lane * 2);
    float sc[4];
#pragma unroll
    for (int hh = 0; hh < 4; hh++) {
      float a = 0.f;
#pragma unroll
      for (int j = 0; j < 4; j++) {
        a = fmaf(kf[j].x, qf[hh][j].x, a);
        a = fmaf(kf[j].y, qf[hh][j].y, a);
        a = fmaf(kf[j].z, qf[hh][j].z, a);
        a = fmaf(kf[j].w, qf[hh][j].w, a);
      }
      a = fmaf(k2.x, q2[hh].x, a);
      a = fmaf(k2.y, q2[hh].y, a);
      sc[hh] = a;
    }
#pragma unroll
    for (int hh = 0; hh < 4; hh++) {
      float v = sc[hh];
#pragma unroll
      for (int o = 1; o < 64; o <<= 1) v += __shfl_xor(v, o, 64);
      if (lane == 0) sc_s[hp * 4 + hh][t] = v;
    }
  }
  // zero the combine buffer while scores finish
  for (int i = tid; i < 8 * 1152; i += 1024) ((float*)vasm)[i] = 0.f;
  __syncthreads();

  // ---- softmax over 256 tokens per head (threads t<256), in-place ----
  const bool act = (tid < 256);
  float p[8];
  if (act) {
#pragma unroll
    for (int h = 0; h < 8; h++) {
      float m = sc_s[h][tid];
#pragma unroll
      for (int o = 1; o < 64; o <<= 1) m = fmaxf(m, __shfl_xor(m, o, 64));
      if (lane == 0) red[wid][h] = m;
    }
  }
  __syncthreads();
  if (act) {
#pragma unroll
    for (int h = 0; h < 8; h++) {
      const float M = fmaxf(fmaxf(red[0][h], red[1][h]), fmaxf(red[2][h], red[3][h]));
      p[h] = __expf(sc_s[h][tid] - M);
      float s = p[h];
#pragma unroll
      for (int o = 1; o < 64; o <<= 1) s += __shfl_xor(s, o, 64);
      if (lane == 0) red2[wid][h] = s;
    }
  }
  __syncthreads();
  if (act) {
#pragma unroll
    for (int h = 0; h < 8; h++) {
      const float S = red2[0][h] + red2[1][h] + red2[2][h] + red2[3][h];
      sc_s[h][tid] = p[h] * (1.0f / S);    // in-place: own element only
    }
  }
  __syncthreads();

  // ---- phase 2: VA partials (coalesced V), LDS-atomic combine ----
  float4 af[4][4]; float2 a2[4];
#pragma unroll
  for (int hh = 0; hh < 4; hh++) {
#pragma unroll
    for (int j = 0; j < 4; j++) af[hh][j] = make_float4(0.f, 0.f, 0.f, 0.f);
    a2[hh] = make_float2(0.f, 0.f);
  }
  for (int tt = 0; tt < 32; tt++) {
    const int t = t0 + tt;
    const float* Vrow = V + ((size_t)bl * 256 + t) * 1152;
    float4 vf[4];
#pragma unroll
    for (int j = 0; j < 4; j++) vf[j] = *(const float4*)(Vrow + j * 256 + lane * 4);
    const float2 v2 = *(const float2*)(Vrow + 1024 + lane * 2);
    float a[4];
#pragma unroll
    for (int hh = 0; hh < 4; hh++) a[hh] = sc_s[hp * 4 + hh][t];  // broadcast
#pragma unroll
    for (int hh = 0; hh < 4; hh++) {
#pragma unroll
      for (int j = 0; j < 4; j++) {
        af[hh][j].x = fmaf(a[hh], vf[j].x, af[hh][j].x);
        af[hh][j].y = fmaf(a[hh], vf[j].y, af[hh][j].y);
        af[hh][j].z = fmaf(a[hh], vf[j].z, af[hh][j].z);
        af[hh][j].w = fmaf(a[hh], vf[j].w, af[hh][j].w);
      }
      a2[hh].x = fmaf(a[hh], v2.x, a2[hh].x);
      a2[hh].y = fmaf(a[hh], v2.y, a2[hh].y);
    }
  }
  // rotated-component LDS atomics: bank = (5*lane + k) % 32 -> conflict-free
#pragma unroll
  for (int hh = 0; hh < 4; hh++) {
    float* dst = &vasm[hp * 4 + hh][0];
#pragma unroll
    for (int j = 0; j < 4; j++) {
      const float4 v = af[hh][j];
#pragma unroll
      for (int k = 0; k < 4; k++) {
        const int c = (lane + k) & 3;
        const float val = (c == 0) ? v.x : (c == 1) ? v.y : (c == 2) ? v.z : v.w;
        atomicAdd(&dst[j * 256 + lane * 4 + c], val);
      }
    }
#pragma unroll
    for (int k = 0; k < 2; k++) {
      const int c = (lane + k) & 1;
      const float val = (c == 0) ? a2[hh].x : a2[hh].y;
      atomicAdd(&dst[1024 + lane * 2 + c], val);
    }
  }
  __syncthreads();
  // coalesced write-out
  float* VAdst = VA + (size_t)bl * 8 * 1152;
  for (int i = tid; i < 8 * 1152; i += 1024) VAdst[i] = ((float*)vasm)[i];
}

// ---------------------------------------------------------------------------
// K4: pooled[b,l, e*8+h] = sum_d VA[b,l,h,d] * Wv[g,d,h*64+e] + bv[g,h*64+e]
// grid (27,8) = (l,h); block 512 = 8 waves (wave = b), lane = e.
// ---------------------------------------------------------------------------
__global__ __launch_bounds__(512) void pv_mat(
    const float* __restrict__ VA, const float* __restrict__ Wv,
    const float* __restrict__ bv, float* __restrict__ pooled)
{
  const int l = blockIdx.x, g = l / 3, h = blockIdx.y;
  const int b = threadIdx.x >> 6, lane = threadIdx.x & 63;
  const float* W = Wv + (size_t)g * 1152 * 512 + h * 64 + lane;
  const float* va = VA + (((size_t)(b * 27 + l)) * 8 + h) * 1152;  // wave-uniform
  float acc = 0.f;
#pragma unroll 4
  for (int d = 0; d < 1152; d++)
    acc = fmaf(va[d], W[(size_t)d * 512], acc);
  pooled[(size_t)(b * 27 + l) * 512 + lane * 8 + h] = acc + bv[g * 512 + h * 64 + lane];
}

// ---------------------------------------------------------------------------
// K5: out[b,l,n] = pooled[b,l,:] @ Wo[g] + bo[g]   (f32)
// grid (27,8), block 256, one n per thread, 8 b's per thread.
// ---------------------------------------------------------------------------
__global__ __launch_bounds__(256) void out_gemm(
    const float* __restrict__ pooled, const float* __restrict__ Wo,
    const float* __restrict__ bo, float* __restrict__ out)
{
  const int l = blockIdx.x, g = l / 3;
  const int n = blockIdx.y * 256 + threadIdx.x;
  __shared__ float pl[8][512];
  for (int i = threadIdx.x; i < 4096; i += 256) {
    const int b = i >> 9, f = i & 511;
    pl[b][f] = pooled[(size_t)(b * 27 + l) * 512 + f];
  }
  __syncthreads();
  const float* W = Wo + (size_t)g * 512 * 2048 + n;
  float acc[8] = {0.f, 0.f, 0.f, 0.f, 0.f, 0.f, 0.f, 0.f};
#pragma unroll 4
  for (int f = 0; f < 512; f++) {
    const float w = W[(size_t)f * 2048];
#pragma unroll
    for (int b = 0; b < 8; b++) acc[b] += pl[b][f] * w;
  }
  const float bb = bo[g * 2048 + n];
#pragma unroll
  for (int b = 0; b < 8; b++)
    out[(size_t)(b * 27 + l) * 2048 + n] = acc[b] + bb;
}

// ---------------------------------------------------------------------------
// sentinel: zero-fill f32 output (absmax would read ~1.06e-1 = max|ref|)
// ---------------------------------------------------------------------------
__global__ __launch_bounds__(256) void zfill(float* __restrict__ out, int n) {
  const int i = blockIdx.x * 256 + threadIdx.x;
  if (i < n) out[i] = 0.f;
}

// ---------------------------------------------------------------------------
extern "C" void kernel_launch(void* const* d_in, const int* in_sizes, int n_in,
                              void* d_out, int out_size, void* d_ws, size_t ws_size,
                              hipStream_t stream)
{
  float* out = (float*)d_out;   // f32 output (verified round 4)

  // ---- config guards ----
  bool ok = (n_in == 11) && (out_size == 8 * 27 * 2048);
  if (ok) {
    const int expect[11] = {
      8 * 27 * 256 * 1152,  // K
      8 * 27 * 256 * 1152,  // V
      27 * 1 * 1152,        // query
      9 * 1152 * 512,       // Wq
      9 * 512,              // bq
      9 * 1152 * 512,       // Wk
      9 * 512,              // bk
      9 * 1152 * 512,       // Wv
      9 * 512,              // bv
      9 * 512 * 2048,       // Wo
      9 * 2048              // bo
    };
    for (int i = 0; i < 11; i++) ok = ok && (in_sizes[i] == expect[i]);
  }
  // ws layout (bytes):
  //   Qp     @ 0         :    55,296
  //   Qk     @ 55,296    :   995,328
  //   VA     @ 1,050,624 : 7,962,624
  //   pooled @ 9,013,248 :   442,368   -> NEED 9,455,616
  const size_t NEED = 9455616;
  ok = ok && (ws_size >= NEED);

  if (!ok) {
    zfill<<<dim3((out_size + 255) / 256), dim3(256), 0, stream>>>(out, out_size);
    return;
  }

  const float* Kin   = (const float*)d_in[0];
  const float* Vin   = (const float*)d_in[1];
  const float* query = (const float*)d_in[2];
  const float* Wq    = (const float*)d_in[3];
  const float* bq    = (const float*)d_in[4];
  const float* Wk    = (const float*)d_in[5];
  const float* Wv    = (const float*)d_in[7];
  const float* bvp   = (const float*)d_in[8];
  const float* Wo    = (const float*)d_in[9];
  const float* bo    = (const float*)d_in[10];
  // bk (d_in[6]) unused: constant over t, cancels in softmax exactly.

  char* ws = (char*)d_ws;
  float* Qpw     = (float*)(ws);
  float* Qkw     = (float*)(ws + 55296);
  float* VAw     = (float*)(ws + 1050624);
  float* pooledw = (float*)(ws + 9013248);

  qproj  <<<dim3(27, 8), dim3(256),  0, stream>>>(query, Wq, bq, Qpw);
  qk_mat <<<dim3(3888),  dim3(256),  0, stream>>>(Qpw, Wk, Qkw);
  attn_va<<<dim3(216),   dim3(1024), 0, stream>>>(Kin, Vin, Qkw, VAw);
  pv_mat <<<dim3(27, 8), dim3(512),  0, stream>>>(VAw, Wv, bvp, pooledw);
  out_gemm<<<dim3(27, 8), dim3(256), 0, stream>>>(pooledw, Wo, bo, out);
}

// Round 12
// 311.879 us; speedup vs baseline: 3.6651x; 1.4217x over previous
//
#include <hip/hip_runtime.h>
#include <stdint.h>

// ---- dims ----
// B=8, L=27, T=256, D=1152, GS=3, G=9, DD=512, H=8, HD=64, NQ=1, OD=2048
// Output dtype: FLOAT32 (verified round 4).
//
// Round 12: de-fuse attention for occupancy (round-11 was latency-bound at
// 0.84 blocks/CU, hbm 14%, VALU 12%):
//   score_k  (216,4)x256 : lane=token, d-quarter per block, Qk via uniform
//                          s_loads (layout [l][d][h]), zero shuffles.
//   softmax_k 216x256    : butterfly softmax, attn[bl][t][h].
//   va_k     (216,3)x384 : thread=d-elem, coalesced V, attn via s_load8,
//                          no LDS, acc[8] regs.
//   pv_mat   (27,8,4)    : d-quarter partials -> psum; out_gemm sums 4.
// Algebra (verified r9-r11): scores = K·Qk (bk cancels in softmax);
// pooled = (attn·V)·Wv + bv. All f32.

// ---------------------------------------------------------------------------
// K1: Qp[l,f] = (query[l,:] @ Wq[g] + bq[g]) * 0.125
// grid (27,8), block 256.
// ---------------------------------------------------------------------------
__global__ __launch_bounds__(256) void qproj(
    const float* __restrict__ query, const float* __restrict__ Wq,
    const float* __restrict__ bq, float* __restrict__ Qp)
{
  const int l = blockIdx.x, g = l / 3;
  const int fb = blockIdx.y * 64;
  __shared__ float q[1152];
  __shared__ float part[4][64];
  for (int i = threadIdx.x; i < 1152; i += 256) q[i] = query[(size_t)l * 1152 + i];
  __syncthreads();
  const int fi = threadIdx.x & 63;
  const int kq = threadIdx.x >> 6;            // 0..3, 288 d's each
  const float* W = Wq + (size_t)g * 1152 * 512 + fb + fi;
  float a0 = 0.f, a1 = 0.f;
  const int d0 = kq * 288;
#pragma unroll 4
  for (int d = d0; d < d0 + 288; d += 2) {
    a0 += q[d]     * W[(size_t)d * 512];
    a1 += q[d + 1] * W[(size_t)(d + 1) * 512];
  }
  part[kq][fi] = a0 + a1;
  __syncthreads();
  if (threadIdx.x < 64) {
    const int f = fb + threadIdx.x;
    float r = part[0][threadIdx.x] + part[1][threadIdx.x]
            + part[2][threadIdx.x] + part[3][threadIdx.x];
    Qp[l * 512 + f] = (r + bq[g * 512 + f]) * 0.125f;
  }
}

// ---------------------------------------------------------------------------
// K2: Qk[l,d,h] = sum_e Qp[l,h*64+e] * Wk[g,d,h*64+e]    (layout [l][d][h]!)
// grid 3888, block 256: 4 threads per (l,h,d), 2-level shuffle reduce.
// ---------------------------------------------------------------------------
__global__ __launch_bounds__(256) void qk_mat(
    const float* __restrict__ Qp, const float* __restrict__ Wk,
    float* __restrict__ Qk)
{
  const int gidx = blockIdx.x * 256 + threadIdx.x;  // 0..995327
  const int eg   = gidx & 3;
  const int item = gidx >> 2;         // 0..248831 = (l,h,d)
  const int l    = item / 9216;
  const int rem  = item % 9216;
  const int h    = rem / 1152;
  const int d    = rem % 1152;
  const int g    = l / 3;
  const float4* q4 = (const float4*)(Qp + l * 512 + h * 64 + eg * 16);
  const float4* w4 = (const float4*)(Wk + (size_t)g * 1152 * 512 + (size_t)d * 512 + h * 64 + eg * 16);
  float acc = 0.f;
#pragma unroll
  for (int e = 0; e < 4; e++) {
    const float4 a = q4[e], b = w4[e];
    acc += a.x * b.x + a.y * b.y + a.z * b.z + a.w * b.w;
  }
  acc += __shfl_xor(acc, 1, 64);
  acc += __shfl_xor(acc, 2, 64);
  if (eg == 0) Qk[((size_t)l * 1152 + d) * 8 + h] = acc;
}

// ---------------------------------------------------------------------------
// K3a: partial scores. grid (216, 4), block 256 (lane = token).
// psc[bl][dq][t][h] = sum_{d in quarter} K[bl,t,d] * Qk[l,d,h]
// K: per-lane row streaming (lines fully consumed); Qk: wave-uniform s_loads.
// ---------------------------------------------------------------------------
__global__ __launch_bounds__(256) void score_k(
    const float* __restrict__ K, const float* __restrict__ Qk,
    float* __restrict__ psc)
{
  const int bl = blockIdx.x;          // 0..215
  const int dq = blockIdx.y;          // 0..3 (d-quarter of 288)
  const int l = bl % 27;
  const int t = threadIdx.x;          // token

  const float4* Kr = (const float4*)(K + ((size_t)bl * 256 + t) * 1152 + dq * 288);
  const float* qk = Qk + ((size_t)l * 1152 + dq * 288) * 8;   // uniform

  float sc[8] = {0.f, 0.f, 0.f, 0.f, 0.f, 0.f, 0.f, 0.f};
#pragma unroll 2
  for (int i = 0; i < 72; i++) {
    const float4 kv = Kr[i];
    const float* q0 = qk + (i * 4) * 8;
#pragma unroll
    for (int h = 0; h < 8; h++) {
      sc[h] = fmaf(kv.x, q0[h],      sc[h]);
      sc[h] = fmaf(kv.y, q0[8 + h],  sc[h]);
      sc[h] = fmaf(kv.z, q0[16 + h], sc[h]);
      sc[h] = fmaf(kv.w, q0[24 + h], sc[h]);
    }
  }
  float* dst = psc + (((size_t)bl * 4 + dq) * 256 + t) * 8;
#pragma unroll
  for (int h = 0; h < 8; h++) dst[h] = sc[h];
}

// ---------------------------------------------------------------------------
// K3b: softmax over 256 tokens per (bl, h). grid 216, block 256 (thread = t).
// attn[bl][t][h] layout (8 contiguous floats per token -> s_load8 in va_k).
// ---------------------------------------------------------------------------
__global__ __launch_bounds__(256) void softmax_k(
    const float* __restrict__ psc, float* __restrict__ attn)
{
  const int bl = blockIdx.x;
  const int t = threadIdx.x;
  const int wid = t >> 6, lane = t & 63;
  __shared__ float red[4][8], red2[4][8];

  float sc[8];
#pragma unroll
  for (int h = 0; h < 8; h++) sc[h] = 0.f;
#pragma unroll
  for (int dq = 0; dq < 4; dq++) {
    const float* src = psc + (((size_t)bl * 4 + dq) * 256 + t) * 8;
#pragma unroll
    for (int h = 0; h < 8; h++) sc[h] += src[h];
  }
#pragma unroll
  for (int h = 0; h < 8; h++) {
    float m = sc[h];
#pragma unroll
    for (int o = 1; o < 64; o <<= 1) m = fmaxf(m, __shfl_xor(m, o, 64));
    if (lane == 0) red[wid][h] = m;
  }
  __syncthreads();
  float p[8];
#pragma unroll
  for (int h = 0; h < 8; h++) {
    const float M = fmaxf(fmaxf(red[0][h], red[1][h]), fmaxf(red[2][h], red[3][h]));
    p[h] = __expf(sc[h] - M);
    float s = p[h];
#pragma unroll
    for (int o = 1; o < 64; o <<= 1) s += __shfl_xor(s, o, 64);
    if (lane == 0) red2[wid][h] = s;
  }
  __syncthreads();
  float* dst = attn + ((size_t)bl * 256 + t) * 8;
#pragma unroll
  for (int h = 0; h < 8; h++) {
    const float S = red2[0][h] + red2[1][h] + red2[2][h] + red2[3][h];
    dst[h] = p[h] * (1.0f / S);
  }
}

// ---------------------------------------------------------------------------
// K3c: VA[bl][h][d] = sum_t attn[bl][t][h] * V[bl,t,d]
// grid (216, 3), block 384 (thread = d-element within third). No LDS.
// V coalesced; attn via wave-uniform s_load (8 contiguous floats per t).
// ---------------------------------------------------------------------------
__global__ __launch_bounds__(384) void va_k(
    const float* __restrict__ V, const float* __restrict__ attn,
    float* __restrict__ VA)
{
  const int bl = blockIdx.x;          // 0..215
  const int dt = blockIdx.y;          // 0..2 (d-third of 384)
  const int d  = dt * 384 + threadIdx.x;

  const float* Vbase = V + (size_t)bl * 256 * 1152 + d;
  const float* ab = attn + (size_t)bl * 256 * 8;   // uniform

  float acc[8] = {0.f, 0.f, 0.f, 0.f, 0.f, 0.f, 0.f, 0.f};
#pragma unroll 4
  for (int t = 0; t < 256; t++) {
    const float v = Vbase[(size_t)t * 1152];
    const float* av = ab + t * 8;     // uniform -> s_load_dwordx8
#pragma unroll
    for (int h = 0; h < 8; h++) acc[h] = fmaf(av[h], v, acc[h]);
  }
  float* dst = VA + (size_t)bl * 8 * 1152 + d;
#pragma unroll
  for (int h = 0; h < 8; h++) dst[(size_t)h * 1152] = acc[h];
}

// ---------------------------------------------------------------------------
// K4: psum[dz][bl][e*8+h] = sum_{d in quarter dz} VA[bl,h,d]*Wv[g,d,h*64+e]
// grid (27,8,4) = (l,h,dz); block 512 = 8 waves (wave = b), lane = e.
// ---------------------------------------------------------------------------
__global__ __launch_bounds__(512) void pv_mat(
    const float* __restrict__ VA, const float* __restrict__ Wv,
    float* __restrict__ psum)
{
  const int l = blockIdx.x, g = l / 3, h = blockIdx.y, dz = blockIdx.z;
  const int b = threadIdx.x >> 6, lane = threadIdx.x & 63;
  const int bl = b * 27 + l;
  const float* W = Wv + (size_t)g * 1152 * 512 + h * 64 + lane;
  const float* va = VA + ((size_t)bl * 8 + h) * 1152;   // wave-uniform
  const int d0 = dz * 288;
  float a0 = 0.f, a1 = 0.f, a2 = 0.f, a3 = 0.f;
#pragma unroll 2
  for (int d = d0; d < d0 + 288; d += 4) {
    a0 = fmaf(va[d],     W[(size_t)(d)     * 512], a0);
    a1 = fmaf(va[d + 1], W[(size_t)(d + 1) * 512], a1);
    a2 = fmaf(va[d + 2], W[(size_t)(d + 2) * 512], a2);
    a3 = fmaf(va[d + 3], W[(size_t)(d + 3) * 512], a3);
  }
  psum[((size_t)dz * 216 + bl) * 512 + lane * 8 + h] = (a0 + a1) + (a2 + a3);
}

// ---------------------------------------------------------------------------
// K5: out[b,l,n] = (sum_dz psum + bv-projected base? no) ...
// out[bl,n] = pooled[bl,:]@Wo[g] + bo[g];  pooled = sum_dz psum + bv_perm
// bv enters pooled as bv[g, h*64+e] at f=e*8+h -> fold during staging.
// grid (27,8), block 256.
// ---------------------------------------------------------------------------
__global__ __launch_bounds__(256) void out_gemm(
    const float* __restrict__ psum, const float* __restrict__ bv,
    const float* __restrict__ Wo, const float* __restrict__ bo,
    float* __restrict__ out)
{
  const int l = blockIdx.x, g = l / 3;
  const int n = blockIdx.y * 256 + threadIdx.x;
  __shared__ float pl[8][512];
  for (int i = threadIdx.x; i < 4096; i += 256) {
    const int b = i >> 9, f = i & 511;
    const int bl = b * 27 + l;
    const int e = f >> 3, h = f & 7;           // f = e*8 + h
    float v = bv[g * 512 + h * 64 + e];
#pragma unroll
    for (int dz = 0; dz < 4; dz++)
      v += psum[((size_t)dz * 216 + bl) * 512 + f];
    pl[b][f] = v;
  }
  __syncthreads();
  const float* W = Wo + (size_t)g * 512 * 2048 + n;
  float acc[8] = {0.f, 0.f, 0.f, 0.f, 0.f, 0.f, 0.f, 0.f};
#pragma unroll 4
  for (int f = 0; f < 512; f++) {
    const float w = W[(size_t)f * 2048];
#pragma unroll
    for (int b = 0; b < 8; b++) acc[b] += pl[b][f] * w;
  }
  const float bb = bo[g * 2048 + n];
#pragma unroll
  for (int b = 0; b < 8; b++)
    out[(size_t)(b * 27 + l) * 2048 + n] = acc[b] + bb;
}

// ---------------------------------------------------------------------------
// sentinel: zero-fill f32 output (absmax would read ~1.06e-1 = max|ref|)
// ---------------------------------------------------------------------------
__global__ __launch_bounds__(256) void zfill(float* __restrict__ out, int n) {
  const int i = blockIdx.x * 256 + threadIdx.x;
  if (i < n) out[i] = 0.f;
}

// ---------------------------------------------------------------------------
extern "C" void kernel_launch(void* const* d_in, const int* in_sizes, int n_in,
                              void* d_out, int out_size, void* d_ws, size_t ws_size,
                              hipStream_t stream)
{
  float* out = (float*)d_out;   // f32 output (verified round 4)

  // ---- config guards ----
  bool ok = (n_in == 11) && (out_size == 8 * 27 * 2048);
  if (ok) {
    const int expect[11] = {
      8 * 27 * 256 * 1152,  // K
      8 * 27 * 256 * 1152,  // V
      27 * 1 * 1152,        // query
      9 * 1152 * 512,       // Wq
      9 * 512,              // bq
      9 * 1152 * 512,       // Wk
      9 * 512,              // bk
      9 * 1152 * 512,       // Wv
      9 * 512,              // bv
      9 * 512 * 2048,       // Wo
      9 * 2048              // bo
    };
    for (int i = 0; i < 11; i++) ok = ok && (in_sizes[i] == expect[i]);
  }
  // ws layout (bytes):
  //   Qp   @ 0          :    55,296
  //   Qk   @ 55,296     :   995,328   (layout [l][d][h])
  //   psc  @ 1,050,624  : 7,077,888   [bl][dq][t][h]
  //   attn @ 8,128,512  : 1,769,472   [bl][t][h]
  //   VA   @ 9,897,984  : 7,962,624   [bl][h][d]
  //   psum @ 17,860,608 : 1,769,472   [dz][bl][f]
  //   NEED = 19,630,080
  const size_t NEED = 19630080;
  ok = ok && (ws_size >= NEED);

  if (!ok) {
    zfill<<<dim3((out_size + 255) / 256), dim3(256), 0, stream>>>(out, out_size);
    return;
  }

  const float* Kin   = (const float*)d_in[0];
  const float* Vin   = (const float*)d_in[1];
  const float* query = (const float*)d_in[2];
  const float* Wq    = (const float*)d_in[3];
  const float* bq    = (const float*)d_in[4];
  const float* Wk    = (const float*)d_in[5];
  const float* Wv    = (const float*)d_in[7];
  const float* bvp   = (const float*)d_in[8];
  const float* Wo    = (const float*)d_in[9];
  const float* bo    = (const float*)d_in[10];
  // bk (d_in[6]) unused: constant over t, cancels in softmax exactly.

  char* ws = (char*)d_ws;
  float* Qpw   = (float*)(ws);
  float* Qkw   = (float*)(ws + 55296);
  float* pscw  = (float*)(ws + 1050624);
  float* attnw = (float*)(ws + 8128512);
  float* VAw   = (float*)(ws + 9897984);
  float* psumw = (float*)(ws + 17860608);

  qproj    <<<dim3(27, 8),    dim3(256), 0, stream>>>(query, Wq, bq, Qpw);
  qk_mat   <<<dim3(3888),     dim3(256), 0, stream>>>(Qpw, Wk, Qkw);
  score_k  <<<dim3(216, 4),   dim3(256), 0, stream>>>(Kin, Qkw, pscw);
  softmax_k<<<dim3(216),      dim3(256), 0, stream>>>(pscw, attnw);
  va_k     <<<dim3(216, 3),   dim3(384), 0, stream>>>(Vin, attnw, VAw);
  pv_mat   <<<dim3(27, 8, 4), dim3(512), 0, stream>>>(VAw, Wv, psumw);
  out_gemm <<<dim3(27, 8),    dim3(256), 0, stream>>>(psumw, bvp, Wo, bo, out);
}